// Round 12
// baseline (99.662 us; speedup 1.0000x reference)
//
#include <hip/hip_runtime.h>
#include <math.h>

#define Bn 8
#define Kn 4
#define Dn 384
#define Ln 4096
#define En 8
#define DTn 16

// ---------------------------------------------------------------------------
// Kernel 1: mh[b,d] = mean over (k,l) of xs[b,k,d,l].   grid = B*D blocks.
// ---------------------------------------------------------------------------
__global__ __launch_bounds__(256) void mean_kernel(const float* __restrict__ xs,
                                                   float* __restrict__ mh) {
    int bd = blockIdx.x;                 // b*Dn + d
    int b = bd / Dn;
    int d = bd % Dn;
    float s = 0.f;
    for (int k = 0; k < Kn; ++k) {
        const float4* row = (const float4*)(xs + (((size_t)b * Kn + k) * Dn + d) * Ln);
        for (int i = threadIdx.x; i < Ln / 4; i += 256) {
            float4 v = row[i];
            s += (v.x + v.y) + (v.z + v.w);
        }
    }
    for (int off = 32; off > 0; off >>= 1) s += __shfl_down(s, off);
    __shared__ float red[4];
    int wid = threadIdx.x >> 6;
    if ((threadIdx.x & 63) == 0) red[wid] = s;
    __syncthreads();
    if (threadIdx.x == 0) {
        float t = (red[0] + red[1]) + (red[2] + red[3]);
        mh[bd] = t * (1.f / (Kn * Ln));
    }
}

// ---------------------------------------------------------------------------
// Kernel 2 (router folded into wc): every block redundantly computes the
// full 8x8 gate in LDS (256 threads = 64 (b,e) pairs x 4 lanes — exact fit;
// mh/route_w/noise_w are L2-hot, ~0.4 us), then computes its 256-element
// chunk of Wct with d-fastest thread mapping (coalesced W reads).
// Block 0 thread 0 writes z_loss. gate never touches global memory.
// ---------------------------------------------------------------------------
__global__ __launch_bounds__(256) void wcrouter_kernel(
        const float* __restrict__ mh, const int* __restrict__ mis_mask,
        const float* __restrict__ route_w, const float* __restrict__ route_b,
        const float* __restrict__ noise_w, const float* __restrict__ noise_b,
        const float* __restrict__ noise, const float* __restrict__ W,
        float* __restrict__ Wct, float* __restrict__ zloss) {
    __shared__ float rl[Bn][En], nl[Bn][En], gl[Bn][En], zb[Bn];
    int t = threadIdx.x;
    {
        int g = t >> 2;                  // group 0..63 -> (b,e)
        int l4 = t & 3;
        int b = g / En, e = g % En;
        const float* m  = mh + b * Dn;
        const float* rw = route_w + e * Dn;
        const float* nw = noise_w + e * Dn;
        float r = 0.f, n = 0.f;
        for (int d = l4; d < Dn; d += 4) {
            float x = m[d];
            r = fmaf(x, rw[d], r);
            n = fmaf(x, nw[d], n);
        }
        r += __shfl_xor(r, 1, 4); r += __shfl_xor(r, 2, 4);
        n += __shfl_xor(n, 1, 4); n += __shfl_xor(n, 2, 4);
        if (l4 == 0) {
            rl[b][e] = r + route_b[e];
            nl[b][e] = n + noise_b[e];
        }
    }
    __syncthreads();
    if (t < Bn) {
        int b = t;
        float lg[En], nn[En], noisy[En], sp[En];
        float mx = -1e30f;
        for (int e = 0; e < En; ++e) mx = fmaxf(mx, rl[b][e]);
        float s = 0.f;
        for (int e = 0; e < En; ++e) { lg[e] = expf(rl[b][e] - mx); s += lg[e]; }
        for (int e = 0; e < En; ++e) lg[e] /= s;
        for (int e = 0; e < En; ++e) {
            float x = nl[b][e];
            float spl = fmaxf(x, 0.f) + log1pf(expf(-fabsf(x)));   // stable softplus
            nn[e] = noise[b * En + e] * spl;
        }
        mx = -1e30f;
        for (int e = 0; e < En; ++e) mx = fmaxf(mx, nn[e]);
        s = 0.f;
        for (int e = 0; e < En; ++e) { nn[e] = expf(nn[e] - mx); s += nn[e]; }
        for (int e = 0; e < En; ++e) noisy[e] = lg[e] + nn[e] / s;
        int kk = mis_mask[b];
        for (int e = 0; e < En; ++e) {
            int rank = 0;
            for (int j = 0; j < En; ++j)
                rank += (noisy[j] > noisy[e]) || (noisy[j] == noisy[e] && j < e);
            sp[e] = (rank < kk) ? noisy[e] : 0.f;
        }
        mx = -1e30f;
        for (int e = 0; e < En; ++e) mx = fmaxf(mx, sp[e]);
        s = 0.f;
        for (int e = 0; e < En; ++e) { sp[e] = expf(sp[e] - mx); s += sp[e]; }
        for (int e = 0; e < En; ++e) gl[b][e] = sp[e] / s;
        mx = -1e30f;
        for (int e = 0; e < En; ++e) mx = fmaxf(mx, noisy[e]);
        s = 0.f;
        for (int e = 0; e < En; ++e) s += expf(noisy[e] - mx);
        float lse = mx + logf(s);
        zb[b] = lse * lse;
    }
    __syncthreads();
    if (blockIdx.x == 0 && t == 0) {
        float z = 0.f;
        for (int b = 0; b < Bn; ++b) z += zb[b];
        zloss[0] = z * (1.f / Bn);
    }
    // phase 2: Wct chunk, d-fastest mapping (coalesced W reads)
    int idx = blockIdx.x * 256 + t;      // exactly Bn*Kn*Dn*DTn threads
    int d  = idx % Dn;
    int r2 = idx / Dn;
    int c  = r2 % DTn;
    int k  = (r2 / DTn) % Kn;
    int b  = r2 / (DTn * Kn);
    float s = 0.f;
#pragma unroll
    for (int e = 0; e < En; ++e)
        s = fmaf(gl[b][e], W[(((size_t)e * Kn + k) * DTn + c) * Dn + d], s);
    Wct[(((size_t)b * Kn + k) * Dn + d) * DTn + c] = s;
}

// ---------------------------------------------------------------------------
// Kernel 3: out[b,k,c,l] = sum_d Wct[b,k,d,c] * xs[b,k,d,l]
// d-split + LDS weights + 8-deep x pipeline (round-10 structure), with the
// reduction LDS OVERLAID on the weight LDS (weights dead by then):
// 24 KB total -> 6 blocks/CU = 24 waves/CU (was 40 KB -> 4 blocks/CU).
// ---------------------------------------------------------------------------
__global__ __launch_bounds__(256, 2) void proj_kernel(const float* __restrict__ xs,
                                                      const float* __restrict__ Wct,
                                                      float* __restrict__ out) {
    const int nlt = Ln / 256;            // 16 l-tiles of 256
    int bk = blockIdx.x / nlt;
    int lt = blockIdx.x % nlt;
    int idx = threadIdx.x & 127;         // l-pair within tile
    int ds  = threadIdx.x >> 7;          // d-half: 0 or 1
    int l = lt * 256 + idx * 2;

    __shared__ float smem[Dn * DTn];     // 24 KB, dual-purpose
    float4* wlds = (float4*)smem;        // [d][q], q=0..3 -> 16 c
    float2* red  = (float2*)smem;        // overlaid [DTn][128] = 16 KB

    {
        const float4* wg = (const float4*)(Wct + (size_t)bk * Dn * DTn);
        for (int i = threadIdx.x; i < Dn * 4; i += 256)
            wlds[i] = wg[i];
    }
    __syncthreads();

    const float* xcol = xs + (size_t)bk * Dn * Ln + l;
    float2 acc[DTn];
#pragma unroll
    for (int c = 0; c < DTn; ++c) { acc[c].x = 0.f; acc[c].y = 0.f; }

    int d0 = ds * (Dn / 2);              // 192 d-rows per half
    for (int dc = 0; dc < Dn / 2; dc += 8) {
        float2 xb[8];                    // 8 independent loads in flight
#pragma unroll
        for (int j = 0; j < 8; ++j)
            xb[j] = *(const float2*)(xcol + (size_t)(d0 + dc + j) * Ln);
#pragma unroll
        for (int j = 0; j < 8; ++j) {
            int d = d0 + dc + j;
            float2 x = xb[j];
#pragma unroll
            for (int q = 0; q < 4; ++q) {
                float4 w = wlds[d * 4 + q];
                acc[q * 4 + 0].x = fmaf(w.x, x.x, acc[q * 4 + 0].x);
                acc[q * 4 + 0].y = fmaf(w.x, x.y, acc[q * 4 + 0].y);
                acc[q * 4 + 1].x = fmaf(w.y, x.x, acc[q * 4 + 1].x);
                acc[q * 4 + 1].y = fmaf(w.y, x.y, acc[q * 4 + 1].y);
                acc[q * 4 + 2].x = fmaf(w.z, x.x, acc[q * 4 + 2].x);
                acc[q * 4 + 2].y = fmaf(w.z, x.y, acc[q * 4 + 2].y);
                acc[q * 4 + 3].x = fmaf(w.w, x.x, acc[q * 4 + 3].x);
                acc[q * 4 + 3].y = fmaf(w.w, x.y, acc[q * 4 + 3].y);
            }
        }
    }

    __syncthreads();                     // all wlds reads done; safe to overlay
    if (ds == 1) {
#pragma unroll
        for (int c = 0; c < DTn; ++c) red[c * 128 + idx] = acc[c];
    }
    __syncthreads();
    if (ds == 0) {
        float* ob = out + (size_t)bk * DTn * Ln + l;
#pragma unroll
        for (int c = 0; c < DTn; ++c) {
            float2 p = red[c * 128 + idx];
            float2 r;
            r.x = acc[c].x + p.x;
            r.y = acc[c].y + p.y;
            *(float2*)(ob + (size_t)c * Ln) = r;
        }
    }
}

extern "C" void kernel_launch(void* const* d_in, const int* in_sizes, int n_in,
                              void* d_out, int out_size, void* d_ws, size_t ws_size,
                              hipStream_t stream) {
    const float* xs       = (const float*)d_in[0];
    const int*   mis_mask = (const int*)d_in[1];
    const float* W        = (const float*)d_in[2];
    const float* route_w  = (const float*)d_in[3];
    const float* route_b  = (const float*)d_in[4];
    const float* noise_w  = (const float*)d_in[5];
    const float* noise_b  = (const float*)d_in[6];
    const float* noise    = (const float*)d_in[7];
    float* out = (float*)d_out;
    float* ws  = (float*)d_ws;

    float* mh    = ws;               // Bn*Dn = 3072 floats
    float* Wct   = ws + 3200;        // Bn*Kn*Dn*DTn = 196608 floats (16B aligned)
    float* zloss = out + (size_t)Bn * Kn * DTn * Ln;   // element 2097152

    hipLaunchKernelGGL(mean_kernel, dim3(Bn * Dn), dim3(256), 0, stream, xs, mh);
    hipLaunchKernelGGL(wcrouter_kernel, dim3(Bn * Kn * Dn * DTn / 256), dim3(256), 0, stream,
                       mh, mis_mask, route_w, route_b, noise_w, noise_b, noise, W, Wct, zloss);
    hipLaunchKernelGGL(proj_kernel, dim3(Bn * Kn * (Ln / 256)), dim3(256), 0, stream,
                       xs, Wct, out);
}

// Round 13
// 82.476 us; speedup vs baseline: 1.2084x; 1.2084x over previous
//
#include <hip/hip_runtime.h>
#include <math.h>

#define Bn 8
#define Kn 4
#define Dn 384
#define Ln 4096
#define En 8
#define DTn 16

// ---------------------------------------------------------------------------
// Kernel 1: mh[b,d] = mean over (k,l) of xs[b,k,d,l].   grid = B*D blocks.
// ---------------------------------------------------------------------------
__global__ __launch_bounds__(256) void mean_kernel(const float* __restrict__ xs,
                                                   float* __restrict__ mh) {
    int bd = blockIdx.x;                 // b*Dn + d
    int b = bd / Dn;
    int d = bd % Dn;
    float s = 0.f;
    for (int k = 0; k < Kn; ++k) {
        const float4* row = (const float4*)(xs + (((size_t)b * Kn + k) * Dn + d) * Ln);
        for (int i = threadIdx.x; i < Ln / 4; i += 256) {
            float4 v = row[i];
            s += (v.x + v.y) + (v.z + v.w);
        }
    }
    for (int off = 32; off > 0; off >>= 1) s += __shfl_down(s, off);
    __shared__ float red[4];
    int wid = threadIdx.x >> 6;
    if ((threadIdx.x & 63) == 0) red[wid] = s;
    __syncthreads();
    if (threadIdx.x == 0) {
        float t = (red[0] + red[1]) + (red[2] + red[3]);
        mh[bd] = t * (1.f / (Kn * Ln));
    }
}

// ---------------------------------------------------------------------------
// Kernel 2: router. One block, 512 threads: 8 lanes per (b,e) pair, float4
// loads (12 per lane per array, 36 independent loads in flight). Round-12
// lesson: the old 4-lane scalar version was ~8-12 us latency-bound.
// ---------------------------------------------------------------------------
__global__ __launch_bounds__(512) void router_kernel(const float* __restrict__ mh, const int* __restrict__ mis_mask,
                              const float* __restrict__ route_w, const float* __restrict__ route_b,
                              const float* __restrict__ noise_w, const float* __restrict__ noise_b,
                              const float* __restrict__ noise, float* __restrict__ gate,
                              float* __restrict__ zloss) {
    __shared__ float rl[Bn][En], nl[Bn][En], zb[Bn];
    int t = threadIdx.x;
    {
        int g  = t >> 3;                 // pair 0..63 -> (b,e)
        int l8 = t & 7;
        int b = g / En, e = g % En;
        const float4* m4  = (const float4*)(mh + b * Dn);
        const float4* rw4 = (const float4*)(route_w + e * Dn);
        const float4* nw4 = (const float4*)(noise_w + e * Dn);
        float r = 0.f, n = 0.f;
#pragma unroll
        for (int i = 0; i < Dn / 4 / 8; ++i) {   // 12 float4 per lane
            float4 x = m4[i * 8 + l8];
            float4 a = rw4[i * 8 + l8];
            float4 c = nw4[i * 8 + l8];
            r = fmaf(x.x, a.x, fmaf(x.y, a.y, fmaf(x.z, a.z, fmaf(x.w, a.w, r))));
            n = fmaf(x.x, c.x, fmaf(x.y, c.y, fmaf(x.z, c.z, fmaf(x.w, c.w, n))));
        }
        r += __shfl_xor(r, 1, 8); r += __shfl_xor(r, 2, 8); r += __shfl_xor(r, 4, 8);
        n += __shfl_xor(n, 1, 8); n += __shfl_xor(n, 2, 8); n += __shfl_xor(n, 4, 8);
        if (l8 == 0) {
            rl[b][e] = r + route_b[e];
            nl[b][e] = n + noise_b[e];
        }
    }
    __syncthreads();
    if (t < Bn) {
        int b = t;
        float lg[En], nn[En], noisy[En], sp[En];
        float mx = -1e30f;
        for (int e = 0; e < En; ++e) mx = fmaxf(mx, rl[b][e]);
        float s = 0.f;
        for (int e = 0; e < En; ++e) { lg[e] = expf(rl[b][e] - mx); s += lg[e]; }
        for (int e = 0; e < En; ++e) lg[e] /= s;
        for (int e = 0; e < En; ++e) {
            float x = nl[b][e];
            float spl = fmaxf(x, 0.f) + log1pf(expf(-fabsf(x)));   // stable softplus
            nn[e] = noise[b * En + e] * spl;
        }
        mx = -1e30f;
        for (int e = 0; e < En; ++e) mx = fmaxf(mx, nn[e]);
        s = 0.f;
        for (int e = 0; e < En; ++e) { nn[e] = expf(nn[e] - mx); s += nn[e]; }
        for (int e = 0; e < En; ++e) noisy[e] = lg[e] + nn[e] / s;
        int kk = mis_mask[b];
        for (int e = 0; e < En; ++e) {
            int rank = 0;
            for (int j = 0; j < En; ++j)
                rank += (noisy[j] > noisy[e]) || (noisy[j] == noisy[e] && j < e);
            sp[e] = (rank < kk) ? noisy[e] : 0.f;
        }
        mx = -1e30f;
        for (int e = 0; e < En; ++e) mx = fmaxf(mx, sp[e]);
        s = 0.f;
        for (int e = 0; e < En; ++e) { sp[e] = expf(sp[e] - mx); s += sp[e]; }
        for (int e = 0; e < En; ++e) gate[b * En + e] = sp[e] / s;
        mx = -1e30f;
        for (int e = 0; e < En; ++e) mx = fmaxf(mx, noisy[e]);
        s = 0.f;
        for (int e = 0; e < En; ++e) s += expf(noisy[e] - mx);
        float lse = mx + logf(s);
        zb[b] = lse * lse;
    }
    __syncthreads();
    if (t == 0) {
        float z = 0.f;
        for (int b = 0; b < Bn; ++b) z += zb[b];
        zloss[0] = z * (1.f / Bn);
    }
}

// ---------------------------------------------------------------------------
// Kernel 3: Wct[b][k][d][c] = sum_e gate[b,e] * W[e][k][c][d]   (transposed)
// ---------------------------------------------------------------------------
__global__ __launch_bounds__(256) void wc_kernel(const float* __restrict__ gate,
                                                 const float* __restrict__ W,
                                                 float* __restrict__ Wct) {
    int idx = blockIdx.x * 256 + threadIdx.x;
    if (idx >= Bn * Kn * Dn * DTn) return;
    int c = idx % DTn;
    int d = (idx / DTn) % Dn;
    int k = (idx / (DTn * Dn)) % Kn;
    int b = idx / (DTn * Dn * Kn);
    float s = 0.f;
#pragma unroll
    for (int e = 0; e < En; ++e)
        s = fmaf(gate[b * En + e], W[(((size_t)e * Kn + k) * DTn + c) * Dn + d], s);
    Wct[idx] = s;
}

// ---------------------------------------------------------------------------
// Kernel 4: out[b,k,c,l] = sum_d Wct[b,k,d,c] * xs[b,k,d,l]
// EXACT round-10 structure (90.8 us build): d-split, LDS weights (24 KB) +
// separate 16 KB reduction LDS (40 KB total -> 4 blocks/CU), 8-deep xb
// pipeline, launch_bounds(256,2).
// ---------------------------------------------------------------------------
__global__ __launch_bounds__(256, 2) void proj_kernel(const float* __restrict__ xs,
                                                      const float* __restrict__ Wct,
                                                      float* __restrict__ out) {
    const int nlt = Ln / 256;            // 16 l-tiles of 256
    int bk = blockIdx.x / nlt;
    int lt = blockIdx.x % nlt;
    int idx = threadIdx.x & 127;         // l-pair within tile
    int ds  = threadIdx.x >> 7;          // d-half: 0 or 1
    int l = lt * 256 + idx * 2;

    // stage Wct[bk] (6144 floats = 24 KB) into LDS, coalesced float4
    __shared__ float4 wlds[Dn * 4];      // [d][q] q=0..3 -> 16 c
    {
        const float4* wg = (const float4*)(Wct + (size_t)bk * Dn * DTn);
        for (int i = threadIdx.x; i < Dn * 4; i += 256)
            wlds[i] = wg[i];
    }
    __syncthreads();

    const float* xcol = xs + (size_t)bk * Dn * Ln + l;
    float2 acc[DTn];
#pragma unroll
    for (int c = 0; c < DTn; ++c) { acc[c].x = 0.f; acc[c].y = 0.f; }

    int d0 = ds * (Dn / 2);              // 192 d-rows per half
    for (int dc = 0; dc < Dn / 2; dc += 8) {
        float2 xb[8];                    // 8 independent loads in flight
#pragma unroll
        for (int j = 0; j < 8; ++j)
            xb[j] = *(const float2*)(xcol + (size_t)(d0 + dc + j) * Ln);
#pragma unroll
        for (int j = 0; j < 8; ++j) {
            int d = d0 + dc + j;
            float2 x = xb[j];
#pragma unroll
            for (int q = 0; q < 4; ++q) {
                float4 w = wlds[d * 4 + q];
                acc[q * 4 + 0].x = fmaf(w.x, x.x, acc[q * 4 + 0].x);
                acc[q * 4 + 0].y = fmaf(w.x, x.y, acc[q * 4 + 0].y);
                acc[q * 4 + 1].x = fmaf(w.y, x.x, acc[q * 4 + 1].x);
                acc[q * 4 + 1].y = fmaf(w.y, x.y, acc[q * 4 + 1].y);
                acc[q * 4 + 2].x = fmaf(w.z, x.x, acc[q * 4 + 2].x);
                acc[q * 4 + 2].y = fmaf(w.z, x.y, acc[q * 4 + 2].y);
                acc[q * 4 + 3].x = fmaf(w.w, x.x, acc[q * 4 + 3].x);
                acc[q * 4 + 3].y = fmaf(w.w, x.y, acc[q * 4 + 3].y);
            }
        }
    }

    // combine the two d-halves through LDS
    __shared__ float2 red[DTn][128];
    if (ds == 1) {
#pragma unroll
        for (int c = 0; c < DTn; ++c) red[c][idx] = acc[c];
    }
    __syncthreads();
    if (ds == 0) {
        float* ob = out + (size_t)bk * DTn * Ln + l;
#pragma unroll
        for (int c = 0; c < DTn; ++c) {
            float2 p = red[c][idx];
            float2 r;
            r.x = acc[c].x + p.x;
            r.y = acc[c].y + p.y;
            *(float2*)(ob + (size_t)c * Ln) = r;
        }
    }
}

extern "C" void kernel_launch(void* const* d_in, const int* in_sizes, int n_in,
                              void* d_out, int out_size, void* d_ws, size_t ws_size,
                              hipStream_t stream) {
    const float* xs       = (const float*)d_in[0];
    const int*   mis_mask = (const int*)d_in[1];
    const float* W        = (const float*)d_in[2];
    const float* route_w  = (const float*)d_in[3];
    const float* route_b  = (const float*)d_in[4];
    const float* noise_w  = (const float*)d_in[5];
    const float* noise_b  = (const float*)d_in[6];
    const float* noise    = (const float*)d_in[7];
    float* out = (float*)d_out;
    float* ws  = (float*)d_ws;

    float* mh    = ws;               // Bn*Dn = 3072 floats
    float* gate  = ws + 3072;        // Bn*En = 64 floats
    float* Wct   = ws + 3200;        // Bn*Kn*Dn*DTn = 196608 floats (16B aligned)
    float* zloss = out + (size_t)Bn * Kn * DTn * Ln;   // element 2097152

    hipLaunchKernelGGL(mean_kernel, dim3(Bn * Dn), dim3(256), 0, stream, xs, mh);
    hipLaunchKernelGGL(router_kernel, dim3(1), dim3(512), 0, stream,
                       mh, mis_mask, route_w, route_b, noise_w, noise_b, noise, gate, zloss);
    hipLaunchKernelGGL(wc_kernel, dim3((Bn * Kn * Dn * DTn + 255) / 256), dim3(256), 0, stream,
                       gate, W, Wct);
    hipLaunchKernelGGL(proj_kernel, dim3(Bn * Kn * (Ln / 256)), dim3(256), 0, stream,
                       xs, Wct, out);
}

// Round 14
// 79.991 us; speedup vs baseline: 1.2459x; 1.0311x over previous
//
#include <hip/hip_runtime.h>
#include <math.h>

#define Bn 8
#define Kn 4
#define Dn 384
#define Ln 4096
#define En 8
#define DTn 16

// ---------------------------------------------------------------------------
// Kernel 1: mh[b,d] = mean over (k,l) of xs[b,k,d,l].   grid = B*D blocks.
// ---------------------------------------------------------------------------
__global__ __launch_bounds__(256) void mean_kernel(const float* __restrict__ xs,
                                                   float* __restrict__ mh) {
    int bd = blockIdx.x;                 // b*Dn + d
    int b = bd / Dn;
    int d = bd % Dn;
    float s = 0.f;
    for (int k = 0; k < Kn; ++k) {
        const float4* row = (const float4*)(xs + (((size_t)b * Kn + k) * Dn + d) * Ln);
        for (int i = threadIdx.x; i < Ln / 4; i += 256) {
            float4 v = row[i];
            s += (v.x + v.y) + (v.z + v.w);
        }
    }
    for (int off = 32; off > 0; off >>= 1) s += __shfl_down(s, off);
    __shared__ float red[4];
    int wid = threadIdx.x >> 6;
    if ((threadIdx.x & 63) == 0) red[wid] = s;
    __syncthreads();
    if (threadIdx.x == 0) {
        float t = (red[0] + red[1]) + (red[2] + red[3]);
        mh[bd] = t * (1.f / (Kn * Ln));
    }
}

// ---------------------------------------------------------------------------
// Kernel 2: router. One block, 512 threads: 8 lanes per (b,e) pair, float4
// loads. (Round-13 verified: removed ~8 us of serial latency.)
// ---------------------------------------------------------------------------
__global__ __launch_bounds__(512) void router_kernel(const float* __restrict__ mh, const int* __restrict__ mis_mask,
                              const float* __restrict__ route_w, const float* __restrict__ route_b,
                              const float* __restrict__ noise_w, const float* __restrict__ noise_b,
                              const float* __restrict__ noise, float* __restrict__ gate,
                              float* __restrict__ zloss) {
    __shared__ float rl[Bn][En], nl[Bn][En], zb[Bn];
    int t = threadIdx.x;
    {
        int g  = t >> 3;                 // pair 0..63 -> (b,e)
        int l8 = t & 7;
        int b = g / En, e = g % En;
        const float4* m4  = (const float4*)(mh + b * Dn);
        const float4* rw4 = (const float4*)(route_w + e * Dn);
        const float4* nw4 = (const float4*)(noise_w + e * Dn);
        float r = 0.f, n = 0.f;
#pragma unroll
        for (int i = 0; i < Dn / 4 / 8; ++i) {   // 12 float4 per lane
            float4 x = m4[i * 8 + l8];
            float4 a = rw4[i * 8 + l8];
            float4 c = nw4[i * 8 + l8];
            r = fmaf(x.x, a.x, fmaf(x.y, a.y, fmaf(x.z, a.z, fmaf(x.w, a.w, r))));
            n = fmaf(x.x, c.x, fmaf(x.y, c.y, fmaf(x.z, c.z, fmaf(x.w, c.w, n))));
        }
        r += __shfl_xor(r, 1, 8); r += __shfl_xor(r, 2, 8); r += __shfl_xor(r, 4, 8);
        n += __shfl_xor(n, 1, 8); n += __shfl_xor(n, 2, 8); n += __shfl_xor(n, 4, 8);
        if (l8 == 0) {
            rl[b][e] = r + route_b[e];
            nl[b][e] = n + noise_b[e];
        }
    }
    __syncthreads();
    if (t < Bn) {
        int b = t;
        float lg[En], nn[En], noisy[En], sp[En];
        float mx = -1e30f;
        for (int e = 0; e < En; ++e) mx = fmaxf(mx, rl[b][e]);
        float s = 0.f;
        for (int e = 0; e < En; ++e) { lg[e] = expf(rl[b][e] - mx); s += lg[e]; }
        for (int e = 0; e < En; ++e) lg[e] /= s;
        for (int e = 0; e < En; ++e) {
            float x = nl[b][e];
            float spl = fmaxf(x, 0.f) + log1pf(expf(-fabsf(x)));   // stable softplus
            nn[e] = noise[b * En + e] * spl;
        }
        mx = -1e30f;
        for (int e = 0; e < En; ++e) mx = fmaxf(mx, nn[e]);
        s = 0.f;
        for (int e = 0; e < En; ++e) { nn[e] = expf(nn[e] - mx); s += nn[e]; }
        for (int e = 0; e < En; ++e) noisy[e] = lg[e] + nn[e] / s;
        int kk = mis_mask[b];
        for (int e = 0; e < En; ++e) {
            int rank = 0;
            for (int j = 0; j < En; ++j)
                rank += (noisy[j] > noisy[e]) || (noisy[j] == noisy[e] && j < e);
            sp[e] = (rank < kk) ? noisy[e] : 0.f;
        }
        mx = -1e30f;
        for (int e = 0; e < En; ++e) mx = fmaxf(mx, sp[e]);
        s = 0.f;
        for (int e = 0; e < En; ++e) { sp[e] = expf(sp[e] - mx); s += sp[e]; }
        for (int e = 0; e < En; ++e) gate[b * En + e] = sp[e] / s;
        mx = -1e30f;
        for (int e = 0; e < En; ++e) mx = fmaxf(mx, noisy[e]);
        s = 0.f;
        for (int e = 0; e < En; ++e) s += expf(noisy[e] - mx);
        float lse = mx + logf(s);
        zb[b] = lse * lse;
    }
    __syncthreads();
    if (t == 0) {
        float z = 0.f;
        for (int b = 0; b < Bn; ++b) z += zb[b];
        zloss[0] = z * (1.f / Bn);
    }
}

// ---------------------------------------------------------------------------
// Kernel 3: out[b,k,c,l] = sum_d (sum_e gate[b,e] W[e,k,c,d]) * xs[b,k,d,l]
// Round-13 proj structure (d-split, 8-deep xb pipeline, LDS weights) with
// the wc kernel FOLDED into the staging phase: each block computes its own
// 24 KB combined-weight slice from W (coalesced d-fastest reads, L2-hot:
// only 4 distinct 192 KB k-slices chip-wide) + gate (8 scalar loads).
// Eliminates the wc launch + gap + Wct global round-trip.
// ---------------------------------------------------------------------------
__global__ __launch_bounds__(256, 2) void proj_kernel(const float* __restrict__ xs,
                                                      const float* __restrict__ gate,
                                                      const float* __restrict__ W,
                                                      float* __restrict__ out) {
    const int nlt = Ln / 256;            // 16 l-tiles of 256
    int bk = blockIdx.x / nlt;
    int b = bk / Kn, k = bk % Kn;
    int lt = blockIdx.x % nlt;
    int idx = threadIdx.x & 127;         // l-pair within tile
    int ds  = threadIdx.x >> 7;          // d-half: 0 or 1
    int l = lt * 256 + idx * 2;

    __shared__ float4 wlds[Dn * 4];      // [d][q] q=0..3 -> 16 c   (24 KB)
    __shared__ float gl[En];
    if (threadIdx.x < En) gl[threadIdx.x] = gate[b * En + threadIdx.x];
    __syncthreads();

    // staging: compute combined weights. 1536 float4s, 6 per thread.
    // fidx -> (d = fidx%Dn, q = fidx/Dn): W reads coalesced (d fastest),
    // ds_write_b128 at <=8-way conflict (6 writes, negligible).
    {
        const float* wk = W + ((size_t)k * DTn) * Dn;   // + e*Kn*DTn*Dn per e
#pragma unroll
        for (int i = 0; i < 6; ++i) {
            int fidx = i * 256 + threadIdx.x;
            int d = fidx % Dn;
            int q = fidx / Dn;           // 0..3
            float4 a = {0.f, 0.f, 0.f, 0.f};
#pragma unroll
            for (int e = 0; e < En; ++e) {
                const float* wb = wk + (size_t)e * Kn * DTn * Dn + d;
                float g = gl[e];
                a.x = fmaf(g, wb[(4 * q + 0) * Dn], a.x);
                a.y = fmaf(g, wb[(4 * q + 1) * Dn], a.y);
                a.z = fmaf(g, wb[(4 * q + 2) * Dn], a.z);
                a.w = fmaf(g, wb[(4 * q + 3) * Dn], a.w);
            }
            wlds[d * 4 + q] = a;
        }
    }
    __syncthreads();

    const float* xcol = xs + (size_t)bk * Dn * Ln + l;
    float2 acc[DTn];
#pragma unroll
    for (int c = 0; c < DTn; ++c) { acc[c].x = 0.f; acc[c].y = 0.f; }

    int d0 = ds * (Dn / 2);              // 192 d-rows per half
    for (int dc = 0; dc < Dn / 2; dc += 8) {
        float2 xb[8];                    // 8 independent loads in flight
#pragma unroll
        for (int j = 0; j < 8; ++j)
            xb[j] = *(const float2*)(xcol + (size_t)(d0 + dc + j) * Ln);
#pragma unroll
        for (int j = 0; j < 8; ++j) {
            int d = d0 + dc + j;
            float2 x = xb[j];
#pragma unroll
            for (int q = 0; q < 4; ++q) {
                float4 w = wlds[d * 4 + q];
                acc[q * 4 + 0].x = fmaf(w.x, x.x, acc[q * 4 + 0].x);
                acc[q * 4 + 0].y = fmaf(w.x, x.y, acc[q * 4 + 0].y);
                acc[q * 4 + 1].x = fmaf(w.y, x.x, acc[q * 4 + 1].x);
                acc[q * 4 + 1].y = fmaf(w.y, x.y, acc[q * 4 + 1].y);
                acc[q * 4 + 2].x = fmaf(w.z, x.x, acc[q * 4 + 2].x);
                acc[q * 4 + 2].y = fmaf(w.z, x.y, acc[q * 4 + 2].y);
                acc[q * 4 + 3].x = fmaf(w.w, x.x, acc[q * 4 + 3].x);
                acc[q * 4 + 3].y = fmaf(w.w, x.y, acc[q * 4 + 3].y);
            }
        }
    }

    // combine the two d-halves through LDS
    __shared__ float2 red[DTn][128];
    if (ds == 1) {
#pragma unroll
        for (int c = 0; c < DTn; ++c) red[c][idx] = acc[c];
    }
    __syncthreads();
    if (ds == 0) {
        float* ob = out + (size_t)bk * DTn * Ln + l;
#pragma unroll
        for (int c = 0; c < DTn; ++c) {
            float2 p = red[c][idx];
            float2 r;
            r.x = acc[c].x + p.x;
            r.y = acc[c].y + p.y;
            *(float2*)(ob + (size_t)c * Ln) = r;
        }
    }
}

extern "C" void kernel_launch(void* const* d_in, const int* in_sizes, int n_in,
                              void* d_out, int out_size, void* d_ws, size_t ws_size,
                              hipStream_t stream) {
    const float* xs       = (const float*)d_in[0];
    const int*   mis_mask = (const int*)d_in[1];
    const float* W        = (const float*)d_in[2];
    const float* route_w  = (const float*)d_in[3];
    const float* route_b  = (const float*)d_in[4];
    const float* noise_w  = (const float*)d_in[5];
    const float* noise_b  = (const float*)d_in[6];
    const float* noise    = (const float*)d_in[7];
    float* out = (float*)d_out;
    float* ws  = (float*)d_ws;

    float* mh    = ws;               // Bn*Dn = 3072 floats
    float* gate  = ws + 3072;        // Bn*En = 64 floats
    float* zloss = out + (size_t)Bn * Kn * DTn * Ln;   // element 2097152

    hipLaunchKernelGGL(mean_kernel, dim3(Bn * Dn), dim3(256), 0, stream, xs, mh);
    hipLaunchKernelGGL(router_kernel, dim3(1), dim3(512), 0, stream,
                       mh, mis_mask, route_w, route_b, noise_w, noise_b, noise, gate, zloss);
    hipLaunchKernelGGL(proj_kernel, dim3(Bn * Kn * (Ln / 256)), dim3(256), 0, stream,
                       xs, gate, W, out);
}

// Round 15
// 79.722 us; speedup vs baseline: 1.2501x; 1.0034x over previous
//
#include <hip/hip_runtime.h>
#include <math.h>
#include <string.h>

#define Bn 8
#define Kn 4
#define Dn 384
#define Ln 4096
#define En 8
#define DTn 16

// ---------------------------------------------------------------------------
// Kernel 1: mh[b,d] = mean over (k,l) of xs[b,k,d,l].   grid = B*D blocks.
// ---------------------------------------------------------------------------
__global__ __launch_bounds__(256) void mean_kernel(const float* __restrict__ xs,
                                                   float* __restrict__ mh) {
    int bd = blockIdx.x;                 // b*Dn + d
    int b = bd / Dn;
    int d = bd % Dn;
    float s = 0.f;
    for (int k = 0; k < Kn; ++k) {
        const float4* row = (const float4*)(xs + (((size_t)b * Kn + k) * Dn + d) * Ln);
        for (int i = threadIdx.x; i < Ln / 4; i += 256) {
            float4 v = row[i];
            s += (v.x + v.y) + (v.z + v.w);
        }
    }
    for (int off = 32; off > 0; off >>= 1) s += __shfl_down(s, off);
    __shared__ float red[4];
    int wid = threadIdx.x >> 6;
    if ((threadIdx.x & 63) == 0) red[wid] = s;
    __syncthreads();
    if (threadIdx.x == 0) {
        float t = (red[0] + red[1]) + (red[2] + red[3]);
        mh[bd] = t * (1.f / (Kn * Ln));
    }
}

// ---------------------------------------------------------------------------
// Kernel 2: router. One block, 512 threads: 8 lanes per (b,e) pair, float4
// loads. (Round-13 verified: removed ~8 us of serial latency.)
// ---------------------------------------------------------------------------
__global__ __launch_bounds__(512) void router_kernel(const float* __restrict__ mh, const int* __restrict__ mis_mask,
                              const float* __restrict__ route_w, const float* __restrict__ route_b,
                              const float* __restrict__ noise_w, const float* __restrict__ noise_b,
                              const float* __restrict__ noise, float* __restrict__ gate,
                              float* __restrict__ zloss) {
    __shared__ float rl[Bn][En], nl[Bn][En], zb[Bn];
    int t = threadIdx.x;
    {
        int g  = t >> 3;                 // pair 0..63 -> (b,e)
        int l8 = t & 7;
        int b = g / En, e = g % En;
        const float4* m4  = (const float4*)(mh + b * Dn);
        const float4* rw4 = (const float4*)(route_w + e * Dn);
        const float4* nw4 = (const float4*)(noise_w + e * Dn);
        float r = 0.f, n = 0.f;
#pragma unroll
        for (int i = 0; i < Dn / 4 / 8; ++i) {   // 12 float4 per lane
            float4 x = m4[i * 8 + l8];
            float4 a = rw4[i * 8 + l8];
            float4 c = nw4[i * 8 + l8];
            r = fmaf(x.x, a.x, fmaf(x.y, a.y, fmaf(x.z, a.z, fmaf(x.w, a.w, r))));
            n = fmaf(x.x, c.x, fmaf(x.y, c.y, fmaf(x.z, c.z, fmaf(x.w, c.w, n))));
        }
        r += __shfl_xor(r, 1, 8); r += __shfl_xor(r, 2, 8); r += __shfl_xor(r, 4, 8);
        n += __shfl_xor(n, 1, 8); n += __shfl_xor(n, 2, 8); n += __shfl_xor(n, 4, 8);
        if (l8 == 0) {
            rl[b][e] = r + route_b[e];
            nl[b][e] = n + noise_b[e];
        }
    }
    __syncthreads();
    if (t < Bn) {
        int b = t;
        float lg[En], nn[En], noisy[En], sp[En];
        float mx = -1e30f;
        for (int e = 0; e < En; ++e) mx = fmaxf(mx, rl[b][e]);
        float s = 0.f;
        for (int e = 0; e < En; ++e) { lg[e] = expf(rl[b][e] - mx); s += lg[e]; }
        for (int e = 0; e < En; ++e) lg[e] /= s;
        for (int e = 0; e < En; ++e) {
            float x = nl[b][e];
            float spl = fmaxf(x, 0.f) + log1pf(expf(-fabsf(x)));   // stable softplus
            nn[e] = noise[b * En + e] * spl;
        }
        mx = -1e30f;
        for (int e = 0; e < En; ++e) mx = fmaxf(mx, nn[e]);
        s = 0.f;
        for (int e = 0; e < En; ++e) { nn[e] = expf(nn[e] - mx); s += nn[e]; }
        for (int e = 0; e < En; ++e) noisy[e] = lg[e] + nn[e] / s;
        int kk = mis_mask[b];
        for (int e = 0; e < En; ++e) {
            int rank = 0;
            for (int j = 0; j < En; ++j)
                rank += (noisy[j] > noisy[e]) || (noisy[j] == noisy[e] && j < e);
            sp[e] = (rank < kk) ? noisy[e] : 0.f;
        }
        mx = -1e30f;
        for (int e = 0; e < En; ++e) mx = fmaxf(mx, sp[e]);
        s = 0.f;
        for (int e = 0; e < En; ++e) { sp[e] = expf(sp[e] - mx); s += sp[e]; }
        for (int e = 0; e < En; ++e) gate[b * En + e] = sp[e] / s;
        mx = -1e30f;
        for (int e = 0; e < En; ++e) mx = fmaxf(mx, noisy[e]);
        s = 0.f;
        for (int e = 0; e < En; ++e) s += expf(noisy[e] - mx);
        float lse = mx + logf(s);
        zb[b] = lse * lse;
    }
    __syncthreads();
    if (t == 0) {
        float z = 0.f;
        for (int b = 0; b < Bn; ++b) z += zb[b];
        zloss[0] = z * (1.f / Bn);
    }
}

// ---------------------------------------------------------------------------
// Kernel 3: out[b,k,c,l] = sum_d (sum_e gate[b,e] W[e,k,c,d]) * xs[b,k,d,l]
// Round-14 structure + (1) first x-chunk loads issued BEFORE weight staging
// (HBM latency hides under staging's L2 reads), (2) explicit 1-chunk-ahead
// software pipeline, (3) nontemporal out stores (write-once data, keep L2
// for W/staging).
// ---------------------------------------------------------------------------
__global__ __launch_bounds__(256, 2) void proj_kernel(const float* __restrict__ xs,
                                                      const float* __restrict__ gate,
                                                      const float* __restrict__ W,
                                                      float* __restrict__ out) {
    const int nlt = Ln / 256;            // 16 l-tiles of 256
    int bk = blockIdx.x / nlt;
    int b = bk / Kn, k = bk % Kn;
    int lt = blockIdx.x % nlt;
    int idx = threadIdx.x & 127;         // l-pair within tile
    int ds  = threadIdx.x >> 7;          // d-half: 0 or 1
    int l = lt * 256 + idx * 2;

    __shared__ float4 wlds[Dn * 4];      // [d][q] q=0..3 -> 16 c   (24 KB)
    __shared__ float gl[En];
    if (threadIdx.x < En) gl[threadIdx.x] = gate[b * En + threadIdx.x];

    const float* xcol = xs + (size_t)bk * Dn * Ln + l;
    int d0 = ds * (Dn / 2);              // 192 d-rows per half

    // (1) issue first x-chunk NOW — lands while staging below does L2 work
    float2 xb[8];
#pragma unroll
    for (int j = 0; j < 8; ++j)
        xb[j] = *(const float2*)(xcol + (size_t)(d0 + j) * Ln);

    __syncthreads();                     // gl visible

    // staging: compute combined weights. 1536 float4s, 6 per thread.
    {
        const float* wk = W + ((size_t)k * DTn) * Dn;
#pragma unroll
        for (int i = 0; i < 6; ++i) {
            int fidx = i * 256 + threadIdx.x;
            int d = fidx % Dn;
            int q = fidx / Dn;           // 0..3
            float4 a = {0.f, 0.f, 0.f, 0.f};
#pragma unroll
            for (int e = 0; e < En; ++e) {
                const float* wb = wk + (size_t)e * Kn * DTn * Dn + d;
                float g = gl[e];
                a.x = fmaf(g, wb[(4 * q + 0) * Dn], a.x);
                a.y = fmaf(g, wb[(4 * q + 1) * Dn], a.y);
                a.z = fmaf(g, wb[(4 * q + 2) * Dn], a.z);
                a.w = fmaf(g, wb[(4 * q + 3) * Dn], a.w);
            }
            wlds[d * 4 + q] = a;
        }
    }
    __syncthreads();

    float2 acc[DTn];
#pragma unroll
    for (int c = 0; c < DTn; ++c) { acc[c].x = 0.f; acc[c].y = 0.f; }

    // (2) 1-chunk-ahead pipeline over 24 chunks of 8 d
    for (int dc = 0; dc < Dn / 2; dc += 8) {
        float2 xn[8];
        if (dc + 8 < Dn / 2) {
#pragma unroll
            for (int j = 0; j < 8; ++j)
                xn[j] = *(const float2*)(xcol + (size_t)(d0 + dc + 8 + j) * Ln);
        }
#pragma unroll
        for (int j = 0; j < 8; ++j) {
            int d = d0 + dc + j;
            float2 x = xb[j];
#pragma unroll
            for (int q = 0; q < 4; ++q) {
                float4 w = wlds[d * 4 + q];
                acc[q * 4 + 0].x = fmaf(w.x, x.x, acc[q * 4 + 0].x);
                acc[q * 4 + 0].y = fmaf(w.x, x.y, acc[q * 4 + 0].y);
                acc[q * 4 + 1].x = fmaf(w.y, x.x, acc[q * 4 + 1].x);
                acc[q * 4 + 1].y = fmaf(w.y, x.y, acc[q * 4 + 1].y);
                acc[q * 4 + 2].x = fmaf(w.z, x.x, acc[q * 4 + 2].x);
                acc[q * 4 + 2].y = fmaf(w.z, x.y, acc[q * 4 + 2].y);
                acc[q * 4 + 3].x = fmaf(w.w, x.x, acc[q * 4 + 3].x);
                acc[q * 4 + 3].y = fmaf(w.w, x.y, acc[q * 4 + 3].y);
            }
        }
#pragma unroll
        for (int j = 0; j < 8; ++j) xb[j] = xn[j];
    }

    // combine the two d-halves through LDS
    __shared__ float2 red[DTn][128];
    if (ds == 1) {
#pragma unroll
        for (int c = 0; c < DTn; ++c) red[c][idx] = acc[c];
    }
    __syncthreads();
    if (ds == 0) {
        float* ob = out + (size_t)bk * DTn * Ln + l;
#pragma unroll
        for (int c = 0; c < DTn; ++c) {
            float2 p = red[c][idx];
            float2 r;
            r.x = acc[c].x + p.x;
            r.y = acc[c].y + p.y;
            // (3) nontemporal 64-bit store — out is write-once
            long long bits;
            memcpy(&bits, &r, 8);
            __builtin_nontemporal_store(bits, (long long*)(ob + (size_t)c * Ln));
        }
    }
}

extern "C" void kernel_launch(void* const* d_in, const int* in_sizes, int n_in,
                              void* d_out, int out_size, void* d_ws, size_t ws_size,
                              hipStream_t stream) {
    const float* xs       = (const float*)d_in[0];
    const int*   mis_mask = (const int*)d_in[1];
    const float* W        = (const float*)d_in[2];
    const float* route_w  = (const float*)d_in[3];
    const float* route_b  = (const float*)d_in[4];
    const float* noise_w  = (const float*)d_in[5];
    const float* noise_b  = (const float*)d_in[6];
    const float* noise    = (const float*)d_in[7];
    float* out = (float*)d_out;
    float* ws  = (float*)d_ws;

    float* mh    = ws;               // Bn*Dn = 3072 floats
    float* gate  = ws + 3072;        // Bn*En = 64 floats
    float* zloss = out + (size_t)Bn * Kn * DTn * Ln;   // element 2097152

    hipLaunchKernelGGL(mean_kernel, dim3(Bn * Dn), dim3(256), 0, stream, xs, mh);
    hipLaunchKernelGGL(router_kernel, dim3(1), dim3(512), 0, stream,
                       mh, mis_mask, route_w, route_b, noise_w, noise_b, noise, gate, zloss);
    hipLaunchKernelGGL(proj_kernel, dim3(Bn * Kn * (Ln / 256)), dim3(256), 0, stream,
                       xs, gate, W, out);
}